// Round 1
// baseline (1097.890 us; speedup 1.0000x reference)
//
#include <hip/hip_runtime.h>
#include <hip/hip_bf16.h>

typedef unsigned int u32;
typedef unsigned short u16;

__device__ __forceinline__ u32 f2bf(float f){
  u32 u = __float_as_uint(f);
  return (u + 0x7fffu + ((u >> 16) & 1u)) >> 16;   // RNE to bf16
}
__device__ __forceinline__ float bflo(u32 p){ return __uint_as_float(p << 16); }
__device__ __forceinline__ float bfhi(u32 p){ return __uint_as_float(p & 0xffff0000u); }

// ---------------- Kernel A: dense projections, packed bf16 output ----------
// out[node*64+c] = pack(x@wA [c], x@wB [c])   (lo = primary, hi = cci)
__global__ __launch_bounds__(256) void proj_kernel(
    const float* __restrict__ xs, const float* __restrict__ xt,
    const float* __restrict__ w_s, const float* __restrict__ w_t,
    const float* __restrict__ w_s_cci, const float* __restrict__ w_t_cci,
    u32* __restrict__ mS, u32* __restrict__ mT, int ns, int nt)
{
  __shared__ float wa[4096], wb[4096];
  const int dir = blockIdx.y;
  const float* x  = dir ? xt : xs;
  const float* wA = dir ? w_t : w_s;
  const float* wB = dir ? w_t_cci : w_s_cci;
  u32* out = dir ? mT : mS;
  const int n = dir ? nt : ns;
  const int tid = threadIdx.x;
  for (int i = tid; i < 4096; i += 256){ wa[i] = wA[i]; wb[i] = wB[i]; }
  __syncthreads();
  const int wid = tid >> 6, lane = tid & 63;
  for (int row = blockIdx.x*4 + wid; row < n; row += gridDim.x*4){
    float xv = x[(size_t)row*64 + lane];
    float accA = 0.f, accB = 0.f;
    #pragma unroll
    for (int k = 0; k < 64; k++){
      float xk = __shfl(xv, k, 64);
      accA = fmaf(xk, wa[k*64 + lane], accA);
      accB = fmaf(xk, wb[k*64 + lane], accB);
    }
    out[(size_t)row*64 + lane] = f2bf(accA) | (f2bf(accB) << 16);
  }
}

// ---------------- Kernel B: histogram ----------------
__global__ __launch_bounds__(256) void hist_kernel(
  const int* __restrict__ rows, const int* __restrict__ cols,
  int* cntR, int* cntC, int E)
{
  int e = blockIdx.x*256 + threadIdx.x;
  if (e < E){
    atomicAdd(&cntR[rows[e]], 1);
    atomicAdd(&cntC[cols[e]], 1);
  }
}

// ---------------- Kernel C: single-block exclusive scan (x2 blocks) --------
__global__ __launch_bounds__(1024) void scan_kernel(
  const int* __restrict__ cntC, const int* __restrict__ cntR,
  int* ptrC, int* ptrR, int* curC, int* curR, int ns, int nt)
{
  __shared__ int lds[1024];
  const int* cnt; int* ptr; int* cur; int n;
  if (blockIdx.x == 0){ cnt=cntC; ptr=ptrC; cur=curC; n=ns; }
  else                { cnt=cntR; ptr=ptrR; cur=curR; n=nt; }
  const int t = threadIdx.x;
  const int C = (n + 1023) / 1024;
  const int base = t*C;
  int s = 0;
  for (int i = 0; i < C; i++){ int idx = base+i; if (idx < n) s += cnt[idx]; }
  lds[t] = s; __syncthreads();
  for (int off = 1; off < 1024; off <<= 1){
    int v = 0; if (t >= off) v = lds[t-off];
    __syncthreads();
    lds[t] += v;
    __syncthreads();
  }
  int run = lds[t] - s;        // exclusive prefix of this chunk
  for (int i = 0; i < C; i++){
    int idx = base+i;
    if (idx < n){ ptr[idx] = run; cur[idx] = run; run += cnt[idx]; }
  }
  if (t == 1023) ptr[n] = lds[1023];
}

// ---------------- Kernel D: scatter edges into CSR (rows) + CSC (cols) -----
__global__ __launch_bounds__(256) void scatter_kernel(
  const int* __restrict__ rows, const int* __restrict__ cols,
  const float* __restrict__ nbv, const float* __restrict__ ccv,
  int* curR, int* curC,
  int* nbrT, float* w0T, float* w1T,
  int* nbrS, float* w0S, float* w1S, int E)
{
  int e = blockIdx.x*256 + threadIdx.x;
  if (e < E){
    int r = rows[e], c = cols[e];
    float a = nbv[e], b = ccv[e];
    int pT = atomicAdd(&curR[r], 1);
    nbrT[pT] = c; w0T[pT] = a; w1T[pT] = b;
    int pS = atomicAdd(&curC[c], 1);
    nbrS[pS] = r; w0S[pS] = a; w1S[pS] = b;
  }
}

// ---------------- Kernel E: per-segment aggregation (1 wave = 1 segment) ---
// stats layout per segment: [s0|s1|s2|mx0|mx1|mx2] x 64 channels, bf16
__global__ __launch_bounds__(256) void agg_kernel(
  const int* __restrict__ ptrC, const int* __restrict__ ptrR,
  const int* __restrict__ nbrS, const float* __restrict__ w0S, const float* __restrict__ w1S,
  const int* __restrict__ nbrT, const float* __restrict__ w0T, const float* __restrict__ w1T,
  const u32* __restrict__ mS, const u32* __restrict__ mT,
  u16* __restrict__ statsS, u16* __restrict__ statsT, int ns, int nt)
{
  const int dir = blockIdx.y;
  const int nseg = dir ? nt : ns;
  const int* ptr = dir ? ptrR : ptrC;
  const int* nbr = dir ? nbrT : nbrS;
  const float* w0 = dir ? w0T : w0S;
  const float* w1 = dir ? w1T : w1S;
  const u32* mtab = dir ? mS : mT;     // msg_src gathers target features & v.v.
  u16* stats = dir ? statsT : statsS;

  const int wid = threadIdx.x >> 6, lane = threadIdx.x & 63;
  const int seg = blockIdx.x*4 + wid;
  if (seg >= nseg) return;
  const int beg = ptr[seg], end = ptr[seg+1];

  float s0=0.f, s1=0.f, s2=0.f;
  float mx0=-INFINITY, mx1=-INFINITY, mx2=-INFINITY;

  int e = beg;
  for (; e + 4 <= end; e += 4){
    int n4[4]; float a4[4], b4[4]; u32 p4[4];
    #pragma unroll
    for (int u=0;u<4;u++){ n4[u]=nbr[e+u]; a4[u]=w0[e+u]; b4[u]=w1[e+u]; }
    #pragma unroll
    for (int u=0;u<4;u++){ p4[u] = mtab[(size_t)n4[u]*64 + lane]; }
    #pragma unroll
    for (int u=0;u<4;u++){
      float g0 = bflo(p4[u]) * a4[u];
      float g1 = bfhi(p4[u]) * b4[u];
      float g2 = g1 * a4[u];
      s0 += g0; s1 += g1; s2 += g2;
      mx0 = fmaxf(mx0, g0); mx1 = fmaxf(mx1, g1); mx2 = fmaxf(mx2, g2);
    }
  }
  for (; e < end; e++){
    int nb = nbr[e]; float a = w0[e], b = w1[e];
    u32 p = mtab[(size_t)nb*64 + lane];
    float g0 = bflo(p) * a;
    float g1 = bfhi(p) * b;
    float g2 = g1 * a;
    s0 += g0; s1 += g1; s2 += g2;
    mx0 = fmaxf(mx0, g0); mx1 = fmaxf(mx1, g1); mx2 = fmaxf(mx2, g2);
  }
  if (end == beg){ mx0 = 0.f; mx1 = 0.f; mx2 = 0.f; }  // empty segment -> 0

  size_t o = (size_t)seg*384 + lane;
  stats[o      ] = (u16)f2bf(s0);
  stats[o + 64 ] = (u16)f2bf(s1);
  stats[o + 128] = (u16)f2bf(s2);
  stats[o + 192] = (u16)f2bf(mx0);
  stats[o + 256] = (u16)f2bf(mx1);
  stats[o + 320] = (u16)f2bf(mx2);
}

// ---------------- Kernel F: per-segment [576] @ [576,64] + b ---------------
__global__ __launch_bounds__(256) void lin_kernel(
  const u16* __restrict__ statsS, const u16* __restrict__ statsT,
  const int* __restrict__ ptrC, const int* __restrict__ ptrR,
  const float* __restrict__ srcW, const float* __restrict__ srcB,
  const float* __restrict__ tgtW, const float* __restrict__ tgtB,
  float* __restrict__ outp, int ns, int nt)
{
  __shared__ float hbuf[16][576];
  __shared__ float Wt[4096];
  __shared__ float invc[16];
  const int dir = blockIdx.y;
  const u16* stats = dir ? statsT : statsS;
  const int* ptr   = dir ? ptrR : ptrC;
  const float* Wg  = dir ? tgtW : srcW;   // [3,192,64] flat == [576,64]
  const float* Bg  = dir ? tgtB : srcB;
  const int n = dir ? nt : ns;
  float* out = outp + (dir ? (size_t)ns*64 : 0);
  const int tid = threadIdx.x;
  const int seg0 = blockIdx.x * 16;
  if (seg0 >= n) return;

  if (tid < 16){
    int seg = seg0 + tid;
    float c = (seg < n) ? (float)(ptr[seg+1] - ptr[seg]) : 1.f;
    invc[tid] = 1.f / fmaxf(c, 1.f);
  }
  __syncthreads();
  // build h = [sum|mean|max] per branch (576 wide) in LDS
  for (int idx = tid; idx < 16*384; idx += 256){
    int s = idx / 384, c = idx % 384;
    int blk = c >> 6, ch = c & 63;
    int seg = seg0 + s;
    float v = 0.f;
    if (seg < n) v = __uint_as_float(((u32)stats[(size_t)seg*384 + c]) << 16);
    if (blk < 3){ hbuf[s][blk*192 + ch] = v; hbuf[s][blk*192 + 64 + ch] = v * invc[s]; }
    else        { hbuf[s][(blk-3)*192 + 128 + ch] = v; }
  }

  const int wid = tid >> 6, lane = tid & 63;
  float acc0=0.f, acc1=0.f, acc2=0.f, acc3=0.f;
  for (int t = 0; t < 9; t++){
    __syncthreads();                     // hbuf ready (t=0) / Wt reuse safe
    for (int idx = tid; idx < 4096; idx += 256) Wt[idx] = Wg[t*4096 + idx];
    __syncthreads();
    #pragma unroll 4
    for (int k = 0; k < 64; k++){
      float wv = Wt[k*64 + lane];
      int kk = t*64 + k;
      acc0 = fmaf(hbuf[wid     ][kk], wv, acc0);
      acc1 = fmaf(hbuf[wid + 4 ][kk], wv, acc1);
      acc2 = fmaf(hbuf[wid + 8 ][kk], wv, acc2);
      acc3 = fmaf(hbuf[wid + 12][kk], wv, acc3);
    }
  }
  float bv = Bg[lane] + Bg[64+lane] + Bg[128+lane];
  int s0i = seg0 + wid;
  if (s0i      < n) out[(size_t)(s0i     )*64 + lane] = acc0 + bv;
  if (s0i + 4  < n) out[(size_t)(s0i + 4 )*64 + lane] = acc1 + bv;
  if (s0i + 8  < n) out[(size_t)(s0i + 8 )*64 + lane] = acc2 + bv;
  if (s0i + 12 < n) out[(size_t)(s0i + 12)*64 + lane] = acc3 + bv;
}

extern "C" void kernel_launch(void* const* d_in, const int* in_sizes, int n_in,
                              void* d_out, int out_size, void* d_ws, size_t ws_size,
                              hipStream_t stream)
{
  const float* xs   = (const float*)d_in[0];
  const float* xt   = (const float*)d_in[1];
  const int*   rows = (const int*)  d_in[2];
  const int*   cols = (const int*)  d_in[3];
  const float* nbv  = (const float*)d_in[4];
  const float* ccv  = (const float*)d_in[5];
  const float* w_s  = (const float*)d_in[6];
  const float* w_t  = (const float*)d_in[7];
  const float* w_sc = (const float*)d_in[8];
  const float* w_tc = (const float*)d_in[9];
  const float* srcW = (const float*)d_in[10];
  const float* srcB = (const float*)d_in[11];
  const float* tgtW = (const float*)d_in[12];
  const float* tgtB = (const float*)d_in[13];
  const int ns = in_sizes[0] / 64;
  const int nt = in_sizes[1] / 64;
  const int E  = in_sizes[4];

  char* ws = (char*)d_ws;
  size_t off = 0;
  auto alloc = [&](size_t bytes)->char* {
    char* p = ws + off;
    off = (off + bytes + 255) & ~(size_t)255;
    return p;
  };
  u32* mS    = (u32*)alloc((size_t)ns*64*4);
  u32* mT    = (u32*)alloc((size_t)nt*64*4);
  int* cntC  = (int*)alloc((size_t)(ns+nt)*4);
  int* cntR  = cntC + ns;
  int* ptrC  = (int*)alloc((size_t)(ns+1)*4);
  int* ptrR  = (int*)alloc((size_t)(nt+1)*4);
  int* curC  = (int*)alloc((size_t)ns*4);
  int* curR  = (int*)alloc((size_t)nt*4);
  int*   nbrS = (int*)  alloc((size_t)E*4);
  float* w0S  = (float*)alloc((size_t)E*4);
  float* w1S  = (float*)alloc((size_t)E*4);
  int*   nbrT = (int*)  alloc((size_t)E*4);
  float* w0T  = (float*)alloc((size_t)E*4);
  float* w1T  = (float*)alloc((size_t)E*4);
  u16* statsS = (u16*)alloc((size_t)ns*384*2);
  u16* statsT = (u16*)alloc((size_t)nt*384*2);

  hipMemsetAsync(cntC, 0, (size_t)(ns+nt)*4, stream);
  proj_kernel<<<dim3(128,2), 256, 0, stream>>>(xs,xt,w_s,w_t,w_sc,w_tc,mS,mT,ns,nt);
  hist_kernel<<<(E+255)/256, 256, 0, stream>>>(rows,cols,cntR,cntC,E);
  scan_kernel<<<2, 1024, 0, stream>>>(cntC,cntR,ptrC,ptrR,curC,curR,ns,nt);
  scatter_kernel<<<(E+255)/256, 256, 0, stream>>>(rows,cols,nbv,ccv,curR,curC,
                                                  nbrT,w0T,w1T,nbrS,w0S,w1S,E);
  const int mseg = (ns > nt ? ns : nt);
  agg_kernel<<<dim3((mseg+3)/4, 2), 256, 0, stream>>>(ptrC,ptrR,nbrS,w0S,w1S,
                                                      nbrT,w0T,w1T,mS,mT,statsS,statsT,ns,nt);
  lin_kernel<<<dim3((mseg+15)/16, 2), 256, 0, stream>>>(statsS,statsT,ptrC,ptrR,
                                                        srcW,srcB,tgtW,tgtB,
                                                        (float*)d_out,ns,nt);
}

// Round 2
// 854.525 us; speedup vs baseline: 1.2848x; 1.2848x over previous
//
#include <hip/hip_runtime.h>
#include <hip/hip_bf16.h>

typedef unsigned int u32;
typedef unsigned short u16;
typedef __attribute__((ext_vector_type(8))) short short8;
typedef __attribute__((ext_vector_type(4))) float f32x4;

__device__ __forceinline__ u32 f2bf(float f){
  u32 u = __float_as_uint(f);
  return (u + 0x7fffu + ((u >> 16) & 1u)) >> 16;   // RNE to bf16
}
__device__ __forceinline__ float bflo(u32 p){ return __uint_as_float(p << 16); }
__device__ __forceinline__ float bfhi(u32 p){ return __uint_as_float(p & 0xffff0000u); }

// ---------------- Kernel A: dense projections, packed bf16 output ----------
// out[node*64+c] = pack(x@wA [c], x@wB [c])   (lo = primary, hi = cci)
__global__ __launch_bounds__(256) void proj_kernel(
    const float* __restrict__ xs, const float* __restrict__ xt,
    const float* __restrict__ w_s, const float* __restrict__ w_t,
    const float* __restrict__ w_s_cci, const float* __restrict__ w_t_cci,
    u32* __restrict__ mS, u32* __restrict__ mT, int ns, int nt)
{
  __shared__ float wa[4096], wb[4096];
  const int dir = blockIdx.y;
  const float* x  = dir ? xt : xs;
  const float* wA = dir ? w_t : w_s;
  const float* wB = dir ? w_t_cci : w_s_cci;
  u32* out = dir ? mT : mS;
  const int n = dir ? nt : ns;
  const int tid = threadIdx.x;
  for (int i = tid; i < 4096; i += 256){ wa[i] = wA[i]; wb[i] = wB[i]; }
  __syncthreads();
  const int wid = tid >> 6, lane = tid & 63;
  for (int row = blockIdx.x*4 + wid; row < n; row += gridDim.x*4){
    float xv = x[(size_t)row*64 + lane];
    float accA = 0.f, accB = 0.f;
    #pragma unroll
    for (int k = 0; k < 64; k++){
      float xk = __shfl(xv, k, 64);
      accA = fmaf(xk, wa[k*64 + lane], accA);
      accB = fmaf(xk, wb[k*64 + lane], accB);
    }
    out[(size_t)row*64 + lane] = f2bf(accA) | (f2bf(accB) << 16);
  }
}

// ---------------- Kernel A2: transpose+cast linear weights -----------------
// Wt[col][k] = bf16(W[k][col]);  W flat [576][64]
__global__ __launch_bounds__(256) void wprep_kernel(
  const float* __restrict__ srcW, const float* __restrict__ tgtW,
  u16* __restrict__ WtS, u16* __restrict__ WtT)
{
  int idx = blockIdx.x*256 + threadIdx.x;
  if (idx < 576*64){
    int col = idx / 576, k = idx - col*576;
    WtS[idx] = (u16)f2bf(srcW[(size_t)k*64 + col]);
    WtT[idx] = (u16)f2bf(tgtW[(size_t)k*64 + col]);
  }
}

// ---------------- Kernel B: histogram ----------------
__global__ __launch_bounds__(256) void hist_kernel(
  const int* __restrict__ rows, const int* __restrict__ cols,
  int* cntR, int* cntC, int E)
{
  int e = blockIdx.x*256 + threadIdx.x;
  if (e < E){
    atomicAdd(&cntR[rows[e]], 1);
    atomicAdd(&cntC[cols[e]], 1);
  }
}

// ---------------- Kernel C: single-block exclusive scan (x2 blocks) --------
__global__ __launch_bounds__(1024) void scan_kernel(
  const int* __restrict__ cntC, const int* __restrict__ cntR,
  int* ptrC, int* ptrR, int* curC, int* curR, int ns, int nt)
{
  __shared__ int lds[1024];
  const int* cnt; int* ptr; int* cur; int n;
  if (blockIdx.x == 0){ cnt=cntC; ptr=ptrC; cur=curC; n=ns; }
  else                { cnt=cntR; ptr=ptrR; cur=curR; n=nt; }
  const int t = threadIdx.x;
  const int C = (n + 1023) / 1024;
  const int base = t*C;
  int s = 0;
  for (int i = 0; i < C; i++){ int idx = base+i; if (idx < n) s += cnt[idx]; }
  lds[t] = s; __syncthreads();
  for (int off = 1; off < 1024; off <<= 1){
    int v = 0; if (t >= off) v = lds[t-off];
    __syncthreads();
    lds[t] += v;
    __syncthreads();
  }
  int run = lds[t] - s;        // exclusive prefix of this chunk
  for (int i = 0; i < C; i++){
    int idx = base+i;
    if (idx < n){ ptr[idx] = run; cur[idx] = run; run += cnt[idx]; }
  }
  if (t == 1023) ptr[n] = lds[1023];
}

// ---------------- Kernel D: scatter edges into CSR (rows) + CSC (cols) -----
__global__ __launch_bounds__(256) void scatter_kernel(
  const int* __restrict__ rows, const int* __restrict__ cols,
  const float* __restrict__ nbv, const float* __restrict__ ccv,
  int* curR, int* curC,
  int* nbrT, float* w0T, float* w1T,
  int* nbrS, float* w0S, float* w1S, int E)
{
  int e = blockIdx.x*256 + threadIdx.x;
  if (e < E){
    int r = rows[e], c = cols[e];
    float a = nbv[e], b = ccv[e];
    int pT = atomicAdd(&curR[r], 1);
    nbrT[pT] = c; w0T[pT] = a; w1T[pT] = b;
    int pS = atomicAdd(&curC[c], 1);
    nbrS[pS] = r; w0S[pS] = a; w1S[pS] = b;
  }
}

// ---------------- Kernel E: per-segment aggregation (1 wave = 1 segment) ---
// stats layout per segment: [s0|s1|s2|mx0|mx1|mx2] x 64 channels, bf16
__global__ __launch_bounds__(256) void agg_kernel(
  const int* __restrict__ ptrC, const int* __restrict__ ptrR,
  const int* __restrict__ nbrS, const float* __restrict__ w0S, const float* __restrict__ w1S,
  const int* __restrict__ nbrT, const float* __restrict__ w0T, const float* __restrict__ w1T,
  const u32* __restrict__ mS, const u32* __restrict__ mT,
  u16* __restrict__ statsS, u16* __restrict__ statsT, int ns, int nt)
{
  const int dir = blockIdx.y;
  const int nseg = dir ? nt : ns;
  const int* ptr = dir ? ptrR : ptrC;
  const int* nbr = dir ? nbrT : nbrS;
  const float* w0 = dir ? w0T : w0S;
  const float* w1 = dir ? w1T : w1S;
  const u32* mtab = dir ? mS : mT;     // msg_src gathers target features & v.v.
  u16* stats = dir ? statsT : statsS;

  const int wid = threadIdx.x >> 6, lane = threadIdx.x & 63;
  const int seg = blockIdx.x*4 + wid;
  if (seg >= nseg) return;
  const int beg = ptr[seg], end = ptr[seg+1];

  float s0=0.f, s1=0.f, s2=0.f;
  float mx0=-INFINITY, mx1=-INFINITY, mx2=-INFINITY;

  int e = beg;
  for (; e + 4 <= end; e += 4){
    int n4[4]; float a4[4], b4[4]; u32 p4[4];
    #pragma unroll
    for (int u=0;u<4;u++){ n4[u]=nbr[e+u]; a4[u]=w0[e+u]; b4[u]=w1[e+u]; }
    #pragma unroll
    for (int u=0;u<4;u++){ p4[u] = mtab[(size_t)n4[u]*64 + lane]; }
    #pragma unroll
    for (int u=0;u<4;u++){
      float g0 = bflo(p4[u]) * a4[u];
      float g1 = bfhi(p4[u]) * b4[u];
      float g2 = g1 * a4[u];
      s0 += g0; s1 += g1; s2 += g2;
      mx0 = fmaxf(mx0, g0); mx1 = fmaxf(mx1, g1); mx2 = fmaxf(mx2, g2);
    }
  }
  for (; e < end; e++){
    int nb = nbr[e]; float a = w0[e], b = w1[e];
    u32 p = mtab[(size_t)nb*64 + lane];
    float g0 = bflo(p) * a;
    float g1 = bfhi(p) * b;
    float g2 = g1 * a;
    s0 += g0; s1 += g1; s2 += g2;
    mx0 = fmaxf(mx0, g0); mx1 = fmaxf(mx1, g1); mx2 = fmaxf(mx2, g2);
  }
  if (end == beg){ mx0 = 0.f; mx1 = 0.f; mx2 = 0.f; }  // empty segment -> 0

  size_t o = (size_t)seg*384 + lane;
  stats[o      ] = (u16)f2bf(s0);
  stats[o + 64 ] = (u16)f2bf(s1);
  stats[o + 128] = (u16)f2bf(s2);
  stats[o + 192] = (u16)f2bf(mx0);
  stats[o + 256] = (u16)f2bf(mx1);
  stats[o + 320] = (u16)f2bf(mx2);
}

// ---------------- Kernel F: MFMA GEMM  [64 segs x 576] @ [576 x 64] --------
// A = h (expanded stats, bf16, LDS, padded rows); B = Wt in registers.
#define HROW 584   // padded LDS row stride in u16 (584*2 B, 16B-aligned, 2-way bank alias only)

__global__ __launch_bounds__(256) void lin_kernel(
  const u16* __restrict__ statsS, const u16* __restrict__ statsT,
  const int* __restrict__ ptrC, const int* __restrict__ ptrR,
  const u16* __restrict__ WtS, const u16* __restrict__ WtT,
  const float* __restrict__ srcB, const float* __restrict__ tgtB,
  float* __restrict__ outp, int ns, int nt)
{
  __shared__ u16 h[64*HROW];
  __shared__ float invc[64];
  const int dir = blockIdx.y;
  const u16* stats = dir ? statsT : statsS;
  const int* ptr   = dir ? ptrR : ptrC;
  const u16* Wt    = dir ? WtT : WtS;
  const float* Bg  = dir ? tgtB : srcB;
  const int n = dir ? nt : ns;
  float* out = outp + (dir ? (size_t)ns*64 : 0);
  const int tid = threadIdx.x;
  const int wv = tid >> 6, lane = tid & 63;
  const int seg0 = blockIdx.x * 64;
  if (seg0 >= n) return;

  // B fragments: wave wv owns cols [wv*16, wv*16+16); lane holds 8 contiguous k
  const int bcol = wv*16 + (lane & 15);
  const int krow = (lane >> 4) * 8;
  short8 bfrag[18];
  #pragma unroll
  for (int t = 0; t < 18; t++)
    bfrag[t] = *(const short8*)&Wt[(size_t)bcol*576 + t*32 + krow];

  if (tid < 64){
    int seg = seg0 + tid;
    float c = (seg < n) ? (float)(ptr[seg+1] - ptr[seg]) : 1.f;
    invc[tid] = 1.f / fmaxf(c, 1.f);
  }
  __syncthreads();

  // stage stats -> h[seg][576] = [sum_p | sum_p/c | max_p] per branch p
  for (int idx = tid; idx < 64*192; idx += 256){
    int s = idx / 192, i = idx - s*192;
    int blk = i >> 5, cp = (i & 31) * 2;
    int seg = seg0 + s;
    u32 v = 0;
    if (seg < n) v = *(const u32*)&stats[(size_t)seg*384 + blk*64 + cp];
    u32* hrow = (u32*)&h[s*HROW];
    if (blk < 3){
      hrow[(blk*192 + cp) >> 1] = v;
      float ic = invc[s];
      hrow[(blk*192 + 64 + cp) >> 1] = f2bf(bflo(v)*ic) | (f2bf(bfhi(v)*ic) << 16);
    } else {
      hrow[((blk-3)*192 + 128 + cp) >> 1] = v;
    }
  }
  __syncthreads();

  f32x4 acc[4] = {};
  const int arow = lane & 15;
  #pragma unroll
  for (int t = 0; t < 18; t++){
    #pragma unroll
    for (int rb = 0; rb < 4; rb++){
      short8 a = *(const short8*)&h[(rb*16 + arow)*HROW + t*32 + krow];
      acc[rb] = __builtin_amdgcn_mfma_f32_16x16x32_bf16(a, bfrag[t], acc[rb], 0, 0, 0);
    }
  }

  float bv = Bg[bcol] + Bg[64 + bcol] + Bg[128 + bcol];
  #pragma unroll
  for (int rb = 0; rb < 4; rb++){
    #pragma unroll
    for (int r = 0; r < 4; r++){
      int seg = seg0 + rb*16 + (lane >> 4)*4 + r;
      if (seg < n) out[(size_t)seg*64 + bcol] = acc[rb][r] + bv;
    }
  }
}

extern "C" void kernel_launch(void* const* d_in, const int* in_sizes, int n_in,
                              void* d_out, int out_size, void* d_ws, size_t ws_size,
                              hipStream_t stream)
{
  const float* xs   = (const float*)d_in[0];
  const float* xt   = (const float*)d_in[1];
  const int*   rows = (const int*)  d_in[2];
  const int*   cols = (const int*)  d_in[3];
  const float* nbv  = (const float*)d_in[4];
  const float* ccv  = (const float*)d_in[5];
  const float* w_s  = (const float*)d_in[6];
  const float* w_t  = (const float*)d_in[7];
  const float* w_sc = (const float*)d_in[8];
  const float* w_tc = (const float*)d_in[9];
  const float* srcW = (const float*)d_in[10];
  const float* srcB = (const float*)d_in[11];
  const float* tgtW = (const float*)d_in[12];
  const float* tgtB = (const float*)d_in[13];
  const int ns = in_sizes[0] / 64;
  const int nt = in_sizes[1] / 64;
  const int E  = in_sizes[4];

  char* ws = (char*)d_ws;
  size_t off = 0;
  auto alloc = [&](size_t bytes)->char* {
    char* p = ws + off;
    off = (off + bytes + 255) & ~(size_t)255;
    return p;
  };
  u32* mS    = (u32*)alloc((size_t)ns*64*4);
  u32* mT    = (u32*)alloc((size_t)nt*64*4);
  int* cntC  = (int*)alloc((size_t)(ns+nt)*4);
  int* cntR  = cntC + ns;
  int* ptrC  = (int*)alloc((size_t)(ns+1)*4);
  int* ptrR  = (int*)alloc((size_t)(nt+1)*4);
  int* curC  = (int*)alloc((size_t)ns*4);
  int* curR  = (int*)alloc((size_t)nt*4);
  int*   nbrS = (int*)  alloc((size_t)E*4);
  float* w0S  = (float*)alloc((size_t)E*4);
  float* w1S  = (float*)alloc((size_t)E*4);
  int*   nbrT = (int*)  alloc((size_t)E*4);
  float* w0T  = (float*)alloc((size_t)E*4);
  float* w1T  = (float*)alloc((size_t)E*4);
  u16* statsS = (u16*)alloc((size_t)ns*384*2);
  u16* statsT = (u16*)alloc((size_t)nt*384*2);
  u16* WtS    = (u16*)alloc((size_t)576*64*2);
  u16* WtT    = (u16*)alloc((size_t)576*64*2);

  hipMemsetAsync(cntC, 0, (size_t)(ns+nt)*4, stream);
  proj_kernel<<<dim3(128,2), 256, 0, stream>>>(xs,xt,w_s,w_t,w_sc,w_tc,mS,mT,ns,nt);
  wprep_kernel<<<(576*64 + 255)/256, 256, 0, stream>>>(srcW,tgtW,WtS,WtT);
  hist_kernel<<<(E+255)/256, 256, 0, stream>>>(rows,cols,cntR,cntC,E);
  scan_kernel<<<2, 1024, 0, stream>>>(cntC,cntR,ptrC,ptrR,curC,curR,ns,nt);
  scatter_kernel<<<(E+255)/256, 256, 0, stream>>>(rows,cols,nbv,ccv,curR,curC,
                                                  nbrT,w0T,w1T,nbrS,w0S,w1S,E);
  const int mseg = (ns > nt ? ns : nt);
  agg_kernel<<<dim3((mseg+3)/4, 2), 256, 0, stream>>>(ptrC,ptrR,nbrS,w0S,w1S,
                                                      nbrT,w0T,w1T,mS,mT,statsS,statsT,ns,nt);
  lin_kernel<<<dim3((mseg+63)/64, 2), 256, 0, stream>>>(statsS,statsT,ptrC,ptrR,
                                                        WtS,WtT,srcB,tgtB,
                                                        (float*)d_out,ns,nt);
}